// Round 9
// baseline (57.286 us; speedup 1.0000x reference)
//
#include <hip/hip_runtime.h>

#define T_STEPS 200
#define BATCH 32
#define N_IN 10000
#define N_OUT 3
#define ROWS (T_STEPS * BATCH)            // 6400
#define STATES (BATCH * N_OUT)            // 96
#define PROJ_N (ROWS * N_OUT)             // 19200
#define NV4 (N_IN / 4)                    // 2500 float4 per row
#define NBLK 2048                         // exactly 8 blocks/CU -> 32 waves/CU (max occupancy)
#define RPB_MAX 4                         // blocks own 3 or 4 rows: rows [b*25/8, (b+1)*25/8)

typedef float f32x4 __attribute__((ext_vector_type(4)));

__device__ __forceinline__ float dot4(f32x4 a, f32x4 b) {
    return a.x * b.x + a.y * b.y + a.z * b.z + a.w * b.w;
}

// Kernel 1: proj[row*3+o] = dot(spikes[row,:], W[o,:]) + b[o]
// 2048 blocks = exactly 8 resident blocks/CU = 32 waves/CU (full occupancy).
// Each block owns 3 or 4 consecutive rows ((b*25)>>3 range split of 25
// rows/CU). Guards are wave-uniform (nr is block-constant) -> no divergence.
// launch_bounds(256,8) caps VGPR at 64 so all 8 blocks/CU co-reside.
__global__ __launch_bounds__(256, 8) void proj_kernel(
    const float* __restrict__ spikes,
    const float* __restrict__ W,
    const float* __restrict__ bias,
    float* __restrict__ proj)             // [ROWS*3] in d_ws
{
    const int b = blockIdx.x;
    const int rs = (b * 25) >> 3;         // first row
    const int nr = (((b + 1) * 25) >> 3) - rs;   // 3 or 4 rows
    const int tid = threadIdx.x;

    const f32x4* __restrict__ s0 = reinterpret_cast<const f32x4*>(spikes + (size_t)rs * N_IN);
    const f32x4* __restrict__ W0 = reinterpret_cast<const f32x4*>(W);
    const f32x4* __restrict__ W1 = reinterpret_cast<const f32x4*>(W + N_IN);
    const f32x4* __restrict__ W2 = reinterpret_cast<const f32x4*>(W + 2 * N_IN);

    float acc[RPB_MAX][3];
    #pragma unroll
    for (int r = 0; r < RPB_MAX; ++r)
        #pragma unroll
        for (int o = 0; o < 3; ++o) acc[r][o] = 0.f;

    for (int i = tid; i < NV4; i += 256) {
        f32x4 s[RPB_MAX];
        #pragma unroll
        for (int r = 0; r < RPB_MAX; ++r)
            if (r < nr) s[r] = s0[(size_t)r * NV4 + i];   // uniform guard per block
        f32x4 w0 = W0[i];
        f32x4 w1 = W1[i];
        f32x4 w2 = W2[i];
        #pragma unroll
        for (int r = 0; r < RPB_MAX; ++r) {
            if (r < nr) {
                acc[r][0] += dot4(s[r], w0);
                acc[r][1] += dot4(s[r], w1);
                acc[r][2] += dot4(s[r], w2);
            }
        }
    }

    #pragma unroll
    for (int r = 0; r < RPB_MAX; ++r)
        #pragma unroll
        for (int o = 0; o < 3; ++o)
            for (int off = 32; off > 0; off >>= 1)
                acc[r][o] += __shfl_down(acc[r][o], off);

    __shared__ float red[4][RPB_MAX][3];
    const int wave = tid >> 6;
    if ((tid & 63) == 0) {
        #pragma unroll
        for (int r = 0; r < RPB_MAX; ++r)
            #pragma unroll
            for (int o = 0; o < 3; ++o)
                red[wave][r][o] = acc[r][o];
    }
    __syncthreads();
    if (tid < nr * 3) {
        const int r = tid / 3, o = tid % 3;
        float s = red[0][r][o] + red[1][r][o] + red[2][r][o] + red[3][r][o];
        proj[(size_t)(rs + r) * 3 + o] = s + bias[o];
    }
}

// Kernel 2: AdaMem scan (R5 proven form). 256 threads stage all of proj
// (76.8 KB) into LDS; first 96 lanes run the 200-step recurrence from LDS
// with an 8-deep register double-buffer (static indexing only).
__global__ __launch_bounds__(256) void scan_kernel(
    const float* __restrict__ proj,       // [T,96] in d_ws
    float* __restrict__ out)              // [2*PROJ_N]: spk_rec then mem_rec
{
    extern __shared__ float lds[];        // PROJ_N floats = 76800 B
    const int tid = threadIdx.x;

    const f32x4* __restrict__ p4 = reinterpret_cast<const f32x4*>(proj);
    f32x4* l4 = reinterpret_cast<f32x4*>(lds);
    #pragma unroll 4
    for (int i = tid; i < PROJ_N / 4; i += 256)
        l4[i] = p4[i];
    __syncthreads();

    const int idx = tid;                  // b*3 + o
    if (idx >= STATES) return;

    float* __restrict__ spk_rec = out;
    float* __restrict__ mem_rec = out + PROJ_N;

    float mem = 0.0f;
    float thr = 1.0f;                     // THR_INIT

    float cur[8], nxt[8];
    #pragma unroll
    for (int k = 0; k < 8; ++k) cur[k] = lds[k * STATES + idx];

    for (int t0 = 0; t0 < T_STEPS; t0 += 8) {
        const int tn = (t0 + 8 < T_STEPS) ? (t0 + 8) : 0;   // last prefetch harmless
        #pragma unroll
        for (int k = 0; k < 8; ++k) nxt[k] = lds[(tn + k) * STATES + idx];
        #pragma unroll
        for (int k = 0; k < 8; ++k) {
            mem = 0.99f * mem + cur[k];              // leaky integration
            float spk = (mem > thr) ? 1.0f : 0.0f;   // fire
            mem -= spk * thr;                        // reset by subtraction
            thr = 0.95f * thr + 5.0f * spk;          // adaptive threshold (BASE_THR=0)
            const int e = (t0 + k) * STATES + idx;
            spk_rec[e] = spk;
            mem_rec[e] = mem;
        }
        #pragma unroll
        for (int k = 0; k < 8; ++k) cur[k] = nxt[k];
    }
}

extern "C" void kernel_launch(void* const* d_in, const int* in_sizes, int n_in,
                              void* d_out, int out_size, void* d_ws, size_t ws_size,
                              hipStream_t stream) {
    const float* spikes = (const float*)d_in[0];   // [200,32,10000]
    const float* W      = (const float*)d_in[1];   // [3,10000]
    const float* b      = (const float*)d_in[2];   // [3]
    float* out  = (float*)d_out;                   // [2,200,32,3] flat
    float* proj = (float*)d_ws;                    // [200,32,3] scratch

    proj_kernel<<<NBLK, 256, 0, stream>>>(spikes, W, b, proj);
    scan_kernel<<<1, 256, PROJ_N * sizeof(float), stream>>>(proj, out);
}

// Round 10
// 52.225 us; speedup vs baseline: 1.0969x; 1.0969x over previous
//
#include <hip/hip_runtime.h>

#define T_STEPS 200
#define BATCH 32
#define N_IN 10000
#define N_OUT 3
#define ROWS (T_STEPS * BATCH)            // 6400
#define STATES (BATCH * N_OUT)            // 96
#define PROJ_N (ROWS * N_OUT)             // 19200
#define NV4 (N_IN / 4)                    // 2500 float4 per row
#define RPB 5                             // rows per block: 6400/5 = 1280 blocks = exactly 5/CU

typedef float f32x4 __attribute__((ext_vector_type(4)));

__device__ __forceinline__ float dot4(f32x4 a, f32x4 b) {
    return a.x * b.x + a.y * b.y + a.z * b.z + a.w * b.w;
}

// Kernel 1: proj[row*3+o] = dot(spikes[row,:], W[o,:]) + b[o]
// PROVEN BEST (R5, 52.9 us). RPB=5 rows/block -> 1280 blocks = exactly 5
// resident blocks per CU (uniform finish, 20 waves/CU). W float4 loaded once
// per iteration, reused across 5 rows (L2-resident). Plain loads — nt and
// explicit pipelining both regressed (R6/R8); 8 blocks/CU regressed (R9).
__global__ __launch_bounds__(256, 5) void proj_kernel(
    const float* __restrict__ spikes,
    const float* __restrict__ W,
    const float* __restrict__ bias,
    float* __restrict__ proj)             // [ROWS*3] in d_ws
{
    const int row0 = blockIdx.x * RPB;
    const int tid = threadIdx.x;

    const f32x4* __restrict__ s0 = reinterpret_cast<const f32x4*>(spikes + (size_t)row0 * N_IN);
    const f32x4* __restrict__ W0 = reinterpret_cast<const f32x4*>(W);
    const f32x4* __restrict__ W1 = reinterpret_cast<const f32x4*>(W + N_IN);
    const f32x4* __restrict__ W2 = reinterpret_cast<const f32x4*>(W + 2 * N_IN);

    float acc[RPB][3];
    #pragma unroll
    for (int r = 0; r < RPB; ++r)
        #pragma unroll
        for (int o = 0; o < 3; ++o) acc[r][o] = 0.f;

    for (int i = tid; i < NV4; i += 256) {
        f32x4 s[RPB];
        #pragma unroll
        for (int r = 0; r < RPB; ++r)
            s[r] = s0[(size_t)r * NV4 + i];
        f32x4 w0 = W0[i];
        f32x4 w1 = W1[i];
        f32x4 w2 = W2[i];
        #pragma unroll
        for (int r = 0; r < RPB; ++r) {
            acc[r][0] += dot4(s[r], w0);
            acc[r][1] += dot4(s[r], w1);
            acc[r][2] += dot4(s[r], w2);
        }
    }

    #pragma unroll
    for (int r = 0; r < RPB; ++r)
        #pragma unroll
        for (int o = 0; o < 3; ++o)
            for (int off = 32; off > 0; off >>= 1)
                acc[r][o] += __shfl_down(acc[r][o], off);

    __shared__ float red[4][RPB][3];
    const int wave = tid >> 6;
    if ((tid & 63) == 0) {
        #pragma unroll
        for (int r = 0; r < RPB; ++r)
            #pragma unroll
            for (int o = 0; o < 3; ++o)
                red[wave][r][o] = acc[r][o];
    }
    __syncthreads();
    if (tid < RPB * 3) {
        const int r = tid / 3, o = tid % 3;
        float s = red[0][r][o] + red[1][r][o] + red[2][r][o] + red[3][r][o];
        proj[(size_t)(row0 + r) * 3 + o] = s + bias[o];
    }
}

// Kernel 2: AdaMem scan (R5 proven form). 256 threads cooperatively stage all
// of proj (76.8 KB) into LDS with parallel float4 loads; first 96 lanes run
// the 200-step recurrence from LDS with an 8-deep register double-buffer
// (static indexing only, rule #20).
__global__ __launch_bounds__(256) void scan_kernel(
    const float* __restrict__ proj,       // [T,96] in d_ws
    float* __restrict__ out)              // [2*PROJ_N]: spk_rec then mem_rec
{
    extern __shared__ float lds[];        // PROJ_N floats = 76800 B
    const int tid = threadIdx.x;

    const f32x4* __restrict__ p4 = reinterpret_cast<const f32x4*>(proj);
    f32x4* l4 = reinterpret_cast<f32x4*>(lds);
    #pragma unroll 4
    for (int i = tid; i < PROJ_N / 4; i += 256)
        l4[i] = p4[i];
    __syncthreads();

    const int idx = tid;                  // b*3 + o
    if (idx >= STATES) return;

    float* __restrict__ spk_rec = out;
    float* __restrict__ mem_rec = out + PROJ_N;

    float mem = 0.0f;
    float thr = 1.0f;                     // THR_INIT

    float cur[8], nxt[8];
    #pragma unroll
    for (int k = 0; k < 8; ++k) cur[k] = lds[k * STATES + idx];

    for (int t0 = 0; t0 < T_STEPS; t0 += 8) {
        const int tn = (t0 + 8 < T_STEPS) ? (t0 + 8) : 0;   // last prefetch harmless
        #pragma unroll
        for (int k = 0; k < 8; ++k) nxt[k] = lds[(tn + k) * STATES + idx];
        #pragma unroll
        for (int k = 0; k < 8; ++k) {
            mem = 0.99f * mem + cur[k];              // leaky integration
            float spk = (mem > thr) ? 1.0f : 0.0f;   // fire
            mem -= spk * thr;                        // reset by subtraction
            thr = 0.95f * thr + 5.0f * spk;          // adaptive threshold (BASE_THR=0)
            const int e = (t0 + k) * STATES + idx;
            spk_rec[e] = spk;
            mem_rec[e] = mem;
        }
        #pragma unroll
        for (int k = 0; k < 8; ++k) cur[k] = nxt[k];
    }
}

extern "C" void kernel_launch(void* const* d_in, const int* in_sizes, int n_in,
                              void* d_out, int out_size, void* d_ws, size_t ws_size,
                              hipStream_t stream) {
    const float* spikes = (const float*)d_in[0];   // [200,32,10000]
    const float* W      = (const float*)d_in[1];   // [3,10000]
    const float* b      = (const float*)d_in[2];   // [3]
    float* out  = (float*)d_out;                   // [2,200,32,3] flat
    float* proj = (float*)d_ws;                    // [200,32,3] scratch

    proj_kernel<<<ROWS / RPB, 256, 0, stream>>>(spikes, W, b, proj);
    scan_kernel<<<1, 256, PROJ_N * sizeof(float), stream>>>(proj, out);
}